// Round 1
// baseline (324.263 us; speedup 1.0000x reference)
//
#include <hip/hip_runtime.h>

#define BATCH   8
#define CDIM    32
#define KLBL    64
#define LDSPAD  33   // pad so bank = (lab + c) % 32 -> spread by random label

// ---------------- Kernel 1: per-batch segment sums ----------------
// grid = (blocks_per_batch, BATCH), block = 256
__global__ __launch_bounds__(256) void seg_sum_kernel(
    const float* __restrict__ pred,   // [B][C][N]
    const int*   __restrict__ label,  // [B][N]
    float* __restrict__ sums,         // [B][K][C]  (global accum, pre-zeroed)
    float* __restrict__ counts,       // [B][K]     (global accum, pre-zeroed)
    int N) {
  __shared__ float s_sums[KLBL * LDSPAD];
  __shared__ float s_counts[KLBL];

  for (int i = threadIdx.x; i < KLBL * LDSPAD; i += blockDim.x) s_sums[i] = 0.f;
  if (threadIdx.x < KLBL) s_counts[threadIdx.x] = 0.f;
  __syncthreads();

  const int b = blockIdx.y;
  const float* __restrict__ pb = pred + (size_t)b * CDIM * N;
  const int*   __restrict__ lb = label + (size_t)b * N;

  for (int n = blockIdx.x * blockDim.x + threadIdx.x; n < N;
       n += gridDim.x * blockDim.x) {
    const int lab = lb[n];
    float v[CDIM];
#pragma unroll
    for (int c = 0; c < CDIM; ++c) v[c] = pb[(size_t)c * N + n];

    atomicAdd(&s_counts[lab], 1.0f);
    float* dst = &s_sums[lab * LDSPAD];
#pragma unroll
    for (int c = 0; c < CDIM; ++c) atomicAdd(&dst[c], v[c]);
  }
  __syncthreads();

  float* gs = sums + (size_t)b * KLBL * CDIM;
  for (int i = threadIdx.x; i < KLBL * CDIM; i += blockDim.x) {
    const int k = i >> 5, c = i & 31;
    atomicAdd(&gs[i], s_sums[k * LDSPAD + c]);
  }
  if (threadIdx.x < KLBL)
    atomicAdd(&counts[b * KLBL + threadIdx.x], s_counts[threadIdx.x]);
}

// ---------------- Kernel 2: centers -> pairwise hinge loss ----------------
// grid = BATCH blocks, block = 256
__global__ __launch_bounds__(256) void loss_kernel(
    const float* __restrict__ sums,    // [B][K][C]
    const float* __restrict__ counts,  // [B][K]
    float* __restrict__ out) {         // scalar (pre-zeroed)
  const int b = blockIdx.x;
  __shared__ float s_center[KLBL * CDIM];  // [k][c]
  __shared__ float s_red[256];

  for (int i = threadIdx.x; i < KLBL * CDIM; i += blockDim.x) {
    const int k = i >> 5;
    const float cnt = fmaxf(counts[b * KLBL + k], 1.0f);
    s_center[i] = sums[(size_t)b * KLBL * CDIM + i] / cnt;
  }
  __syncthreads();

  float acc = 0.f;
  for (int p = threadIdx.x; p < CDIM * CDIM; p += blockDim.x) {
    const int i = p >> 5, j = p & 31;
    float g = 0.f, ni = 0.f, nj = 0.f;
#pragma unroll
    for (int k = 0; k < KLBL; ++k) {
      const float ci = s_center[k * CDIM + i];  // broadcast within lane group
      const float cj = s_center[k * CDIM + j];  // distinct banks
      g  += ci * cj;
      ni += ci * ci;
      nj += cj * cj;
    }
    float sq = ni + nj - 2.f * g;
    sq = fmaxf(sq, 0.f);
    const float dist = (sq > 0.f) ? sqrtf(sq) : 0.f;
    const float h = fmaxf(3.0f - dist, 0.f);  // 2*D_DIST = 3.0
    acc += h * h;
  }

  s_red[threadIdx.x] = acc;
  __syncthreads();
  for (int s = 128; s > 0; s >>= 1) {
    if (threadIdx.x < s) s_red[threadIdx.x] += s_red[threadIdx.x + s];
    __syncthreads();
  }
  if (threadIdx.x == 0) {
    const float loss_b = s_red[0] / (2.0f * (float)KLBL * ((float)KLBL - 1.0f));
    atomicAdd(out, loss_b);
  }
}

// ---------------- launch ----------------
extern "C" void kernel_launch(void* const* d_in, const int* in_sizes, int n_in,
                              void* d_out, int out_size, void* d_ws, size_t ws_size,
                              hipStream_t stream) {
  const float* pred  = (const float*)d_in[0];
  const int*   label = (const int*)d_in[1];
  float* out = (float*)d_out;

  float* sums   = (float*)d_ws;
  float* counts = sums + BATCH * KLBL * CDIM;

  const int N = in_sizes[1] / BATCH;  // 200000

  const size_t accum_bytes = (size_t)(BATCH * KLBL * CDIM + BATCH * KLBL) * sizeof(float);
  hipMemsetAsync(d_ws, 0, accum_bytes, stream);
  hipMemsetAsync(d_out, 0, sizeof(float), stream);

  dim3 grid1(128, BATCH);
  seg_sum_kernel<<<grid1, 256, 0, stream>>>(pred, label, sums, counts, N);
  loss_kernel<<<BATCH, 256, 0, stream>>>(sums, counts, out);
}